// Round 1
// baseline (30822.028 us; speedup 1.0000x reference)
//
#include <hip/hip_runtime.h>
#include <math.h>

// Problem constants
#define VOCAB 32000
#define EMB   256
#define HID   512
#define NB    32
#define TT    128
#define TM1   127
#define SS    128
#define NROWS (TM1*NB)   // 4064
#define NTILES 500       // 32000 / 64

// Workspace layout (float offsets)
//  encW  : (32,128,512)  enc @ attnW[:,512:].T + attnb   (time-invariant)
//  h,c   : ping-pong state [buf][layer][b][j], 2*2*32*512 each
//  cat   : (127,32,1024)  per-step [h1_t, weighted_t] rows
//  part  : (4064, 500) float2 partial (max, sumexp) per fc tile
//  nll/cnt: per-row loss pieces
#define OFF_ENCW 0
#define OFF_H    2097152
#define OFF_C    2162688
#define OFF_CAT  2228224
#define OFF_PART 6389760
#define OFF_NLL  10453760
#define OFF_CNT  10457824
// total: 10461888 floats = 41.9 MB

__device__ __forceinline__ float sigm(float x){ return 1.f/(1.f + expf(-x)); }

// ---------------------------------------------------------------- init states
__global__ void k_init(const float* __restrict__ hid, const float* __restrict__ cel,
                       float* __restrict__ ws){
    int idx = blockIdx.x*256 + threadIdx.x;      // 2*32*512 = 32768
    if (idx >= 2*NB*HID) return;
    int l = idx / (NB*HID);
    int r = idx % (NB*HID);
    ws[OFF_H + l*(NB*HID) + r] = 0.5f*(hid[(2*l)*(NB*HID) + r] + hid[(2*l+1)*(NB*HID) + r]);
    ws[OFF_C + l*(NB*HID) + r] = 0.5f*(cel[(2*l)*(NB*HID) + r] + cel[(2*l+1)*(NB*HID) + r]);
}

// ------------------------------------------------- encW = enc @ attnW_enc^T + b
// M=4096 (b*s), N=512, K=512, tiles 64x64, kc=32
__global__ void k_encw(const float* __restrict__ enc, const float* __restrict__ attnW,
                       const float* __restrict__ attnb, float* __restrict__ ws){
    __shared__ float As[64][33];
    __shared__ float Bs[64][33];
    int tid = threadIdx.x;
    int nt = blockIdx.x, mt = blockIdx.y;
    int m0 = mt*64, n0 = nt*64;
    int ty = tid >> 4, tx = tid & 15;
    float acc[4][4] = {};
    for (int kk = 0; kk < 16; ++kk){
        int k0 = kk*32;
        #pragma unroll
        for (int i = 0; i < 8; ++i){
            int idx = tid + i*256;
            int r = idx >> 5, k = idx & 31;
            As[r][k] = enc[(m0+r)*HID + k0 + k];
            Bs[r][k] = attnW[(n0+r)*1024 + 512 + k0 + k];
        }
        __syncthreads();
        #pragma unroll
        for (int k = 0; k < 32; ++k){
            float av[4], bv[4];
            #pragma unroll
            for (int i=0;i<4;i++) av[i] = As[ty*4+i][k];
            #pragma unroll
            for (int j=0;j<4;j++) bv[j] = Bs[tx*4+j][k];
            #pragma unroll
            for (int i=0;i<4;i++)
                #pragma unroll
                for (int j=0;j<4;j++) acc[i][j] += av[i]*bv[j];
        }
        __syncthreads();
    }
    #pragma unroll
    for (int i=0;i<4;i++)
      #pragma unroll
      for (int j=0;j<4;j++){
        int m = m0 + ty*4+i, n = n0 + tx*4+j;
        ws[OFF_ENCW + m*HID + n] = acc[i][j] + attnb[n];
      }
}

// --------------------------------------------------------------- LSTM layer 0
// gates = emb[X[:,t]] @ Wih0^T + h0_old @ Whh0^T + b ; then cell update.
// 64 blocks (j-tile=8), 256 thr; thread owns (b, j) and its 4 gates.
__global__ void k_lstm0(const int* __restrict__ X, const float* __restrict__ emb,
                        const float* __restrict__ Wih0, const float* __restrict__ Whh0,
                        const float* __restrict__ bih0, const float* __restrict__ bhh0,
                        float* __restrict__ ws, int t, int rb, int wb){
    __shared__ float Hs[32][33];
    __shared__ float Ws[32][33];
    int tid = threadIdx.x;
    int j = tid & 7, b = tid >> 3;
    int jt = blockIdx.x;
    int J = jt*8 + j;
    float acc[4] = {0.f,0.f,0.f,0.f};

    // source 0: embedding rows (K=256) vs Wih0
    for (int kk = 0; kk < 8; ++kk){
        int k0 = kk*32;
        #pragma unroll
        for (int i=0;i<4;i++){
            int idx = tid + i*256;
            int r = idx >> 5, k = idx & 31;
            Hs[r][k] = emb[(long)X[r*TT + t]*EMB + k0 + k];
            int g = r >> 3, jj = r & 7;
            Ws[r][k] = Wih0[(g*HID + jt*8 + jj)*EMB + k0 + k];
        }
        __syncthreads();
        #pragma unroll
        for (int k=0;k<32;k++){
            float hv = Hs[b][k];
            #pragma unroll
            for (int g=0; g<4; g++) acc[g] += Ws[g*8+j][k]*hv;
        }
        __syncthreads();
    }
    // source 1: h0_old (K=512) vs Whh0
    const float* hOld = ws + OFF_H + (rb*2 + 0)*(NB*HID);
    for (int kk = 0; kk < 16; ++kk){
        int k0 = kk*32;
        #pragma unroll
        for (int i=0;i<4;i++){
            int idx = tid + i*256;
            int r = idx >> 5, k = idx & 31;
            Hs[r][k] = hOld[r*HID + k0 + k];
            int g = r >> 3, jj = r & 7;
            Ws[r][k] = Whh0[(g*HID + jt*8 + jj)*HID + k0 + k];
        }
        __syncthreads();
        #pragma unroll
        for (int k=0;k<32;k++){
            float hv = Hs[b][k];
            #pragma unroll
            for (int g=0; g<4; g++) acc[g] += Ws[g*8+j][k]*hv;
        }
        __syncthreads();
    }
    float gi = acc[0] + bih0[J]         + bhh0[J];
    float gf = acc[1] + bih0[HID+J]     + bhh0[HID+J];
    float gg = acc[2] + bih0[2*HID+J]   + bhh0[2*HID+J];
    float go = acc[3] + bih0[3*HID+J]   + bhh0[3*HID+J];
    float cold = ws[OFF_C + (rb*2+0)*(NB*HID) + b*HID + J];
    float cn = sigm(gf)*cold + sigm(gi)*tanhf(gg);
    float hn = sigm(go)*tanhf(cn);
    ws[OFF_H + (wb*2+0)*(NB*HID) + b*HID + J] = hn;
    ws[OFF_C + (wb*2+0)*(NB*HID) + b*HID + J] = cn;
}

// --------------------------------------------------------------- LSTM layer 1
__global__ void k_lstm1(const float* __restrict__ Wih1, const float* __restrict__ Whh1,
                        const float* __restrict__ bih1, const float* __restrict__ bhh1,
                        float* __restrict__ ws, int t, int rb, int wb){
    __shared__ float Hs[32][33];
    __shared__ float Ws[32][33];
    int tid = threadIdx.x;
    int j = tid & 7, b = tid >> 3;
    int jt = blockIdx.x;
    int J = jt*8 + j;
    float acc[4] = {0.f,0.f,0.f,0.f};
    const float* srcA0 = ws + OFF_H + (wb*2+0)*(NB*HID);  // h0 new
    const float* srcA1 = ws + OFF_H + (rb*2+1)*(NB*HID);  // h1 old
    for (int s2 = 0; s2 < 2; ++s2){
        const float* A = s2 ? srcA1 : srcA0;
        const float* W = s2 ? Whh1  : Wih1;
        for (int kk = 0; kk < 16; ++kk){
            int k0 = kk*32;
            #pragma unroll
            for (int i=0;i<4;i++){
                int idx = tid + i*256;
                int r = idx >> 5, k = idx & 31;
                Hs[r][k] = A[r*HID + k0 + k];
                int g = r >> 3, jj = r & 7;
                Ws[r][k] = W[(g*HID + jt*8 + jj)*HID + k0 + k];
            }
            __syncthreads();
            #pragma unroll
            for (int k=0;k<32;k++){
                float hv = Hs[b][k];
                #pragma unroll
                for (int g=0;g<4;g++) acc[g] += Ws[g*8+j][k]*hv;
            }
            __syncthreads();
        }
    }
    float gi = acc[0] + bih1[J]       + bhh1[J];
    float gf = acc[1] + bih1[HID+J]   + bhh1[HID+J];
    float gg = acc[2] + bih1[2*HID+J] + bhh1[2*HID+J];
    float go = acc[3] + bih1[3*HID+J] + bhh1[3*HID+J];
    float cold = ws[OFF_C + (rb*2+1)*(NB*HID) + b*HID + J];
    float cn = sigm(gf)*cold + sigm(gi)*tanhf(gg);
    float hn = sigm(go)*tanhf(cn);
    ws[OFF_H + (wb*2+1)*(NB*HID) + b*HID + J] = hn;
    ws[OFF_C + (wb*2+1)*(NB*HID) + b*HID + J] = cn;
    ws[OFF_CAT + (t*NB + b)*1024 + J] = hn;    // concat row, first half
}

// ----------------------------------------------------------------- attention
// one block per batch element b
__global__ void k_attn(const float* __restrict__ enc, const float* __restrict__ attnW,
                       const float* __restrict__ v, float* __restrict__ ws, int t, int wb){
    __shared__ float h1s[512], vv[512], hqw[512];
    __shared__ float red[256];
    __shared__ float sc[128], att[128];
    int b = blockIdx.x, tid = threadIdx.x;
    const float* h1 = ws + OFF_H + (wb*2+1)*(NB*HID) + b*HID;
    h1s[tid] = h1[tid];        h1s[tid+256] = h1[tid+256];
    vv[tid]  = v[tid];         vv[tid+256]  = v[tid+256];
    __syncthreads();
    // hqW = h1 @ attnW[:, :512]^T
    for (int hh = tid; hh < 512; hh += 256){
        const float* wr = attnW + hh*1024;
        float a = 0.f;
        for (int k=0;k<512;k++) a += wr[k]*h1s[k];
        hqw[hh] = a;
    }
    __syncthreads();
    // scores[s] = sum_k tanh(hqw[k] + encW[b,s,k]) * v[k]  (2 threads per s)
    {
        int s = tid & 127, half = tid >> 7;
        const float* er = ws + OFF_ENCW + (b*SS + s)*HID + half*256;
        const float* hq = hqw + half*256;
        const float* vp = vv  + half*256;
        float a = 0.f;
        for (int k=0;k<256;k++) a += tanhf(hq[k] + er[k]) * vp[k];
        red[tid] = a;
    }
    __syncthreads();
    if (tid < 128) sc[tid] = red[tid] + red[tid+128];
    __syncthreads();
    // softmax over 128
    if (tid < 64) red[tid] = fmaxf(sc[tid], sc[tid+64]);
    __syncthreads();
    for (int off=32; off>=1; off>>=1){
        if (tid < off) red[tid] = fmaxf(red[tid], red[tid+off]);
        __syncthreads();
    }
    float mx = red[0];
    __syncthreads();
    if (tid < 128) att[tid] = expf(sc[tid] - mx);
    __syncthreads();
    if (tid < 64) red[tid] = att[tid] + att[tid+64];
    __syncthreads();
    for (int off=32; off>=1; off>>=1){
        if (tid < off) red[tid] += red[tid+off];
        __syncthreads();
    }
    float inv = 1.f / red[0];
    __syncthreads();
    if (tid < 128) att[tid] *= inv;
    __syncthreads();
    // weighted[h] = sum_s att[s] * enc[b,s,h]
    for (int hh = tid; hh < 512; hh += 256){
        float a = 0.f;
        for (int s=0;s<128;s++) a += att[s]*enc[(b*SS+s)*HID + hh];
        ws[OFF_CAT + (t*NB + b)*1024 + 512 + hh] = a;  // concat row, second half
    }
}

// --------------------------------- fc GEMM + per-tile (max, sumexp) epilogue
// M=4064, N=32000, K=1024; 64x64 tiles, kc=32
__global__ void k_fc(const float* __restrict__ fcW, const float* __restrict__ fcb,
                     float* __restrict__ ws){
    __shared__ float As[64][33];
    __shared__ float Bs[64][33];
    __shared__ float Ls[64][65];
    __shared__ float rm4[64][4];
    __shared__ float rs4[64][4];
    __shared__ float rowm[64];
    int tid = threadIdx.x;
    int nt = blockIdx.x, mt = blockIdx.y;
    int n0 = nt*64, m0 = mt*64;
    int ty = tid >> 4, tx = tid & 15;
    const float* cat = ws + OFF_CAT;
    float acc[4][4] = {};
    for (int kk = 0; kk < 32; ++kk){
        int k0 = kk*32;
        #pragma unroll
        for (int i=0;i<8;i++){
            int idx = tid + i*256;
            int r = idx>>5, k = idx&31;
            int gm = m0 + r;
            As[r][k] = (gm < NROWS) ? cat[gm*1024 + k0+k] : 0.f;
            Bs[r][k] = fcW[(n0+r)*1024 + k0+k];
        }
        __syncthreads();
        #pragma unroll
        for (int k=0;k<32;k++){
            float av[4], bv[4];
            #pragma unroll
            for (int i=0;i<4;i++) av[i] = As[ty*4+i][k];
            #pragma unroll
            for (int j=0;j<4;j++) bv[j] = Bs[tx*4+j][k];
            #pragma unroll
            for (int i=0;i<4;i++)
                #pragma unroll
                for (int j=0;j<4;j++) acc[i][j] += av[i]*bv[j];
        }
        __syncthreads();
    }
    #pragma unroll
    for (int i=0;i<4;i++)
      #pragma unroll
      for (int j=0;j<4;j++)
        Ls[ty*4+i][tx*4+j] = acc[i][j] + fcb[n0 + tx*4+j];
    __syncthreads();
    int row = tid >> 2, q = tid & 3;
    float lm = -3.4e38f;
    for (int c = q*16; c < q*16+16; ++c) lm = fmaxf(lm, Ls[row][c]);
    rm4[row][q] = lm;
    __syncthreads();
    if (q == 0) rowm[row] = fmaxf(fmaxf(rm4[row][0],rm4[row][1]),
                                  fmaxf(rm4[row][2],rm4[row][3]));
    __syncthreads();
    float M = rowm[row];
    float rs = 0.f;
    for (int c = q*16; c < q*16+16; ++c) rs += expf(Ls[row][c] - M);
    rs4[row][q] = rs;
    __syncthreads();
    if (q == 0){
        int gm = m0 + row;
        if (gm < NROWS){
            float S = rs4[row][0]+rs4[row][1]+rs4[row][2]+rs4[row][3];
            float2* p = (float2*)(ws + OFF_PART);
            p[(long)gm*NTILES + nt] = make_float2(M, S);
        }
    }
}

// ------------------------------------- per-row: LSE combine + target logit
__global__ void k_row(const int* __restrict__ X, const float* __restrict__ fcW,
                      const float* __restrict__ fcb, float* __restrict__ ws){
    __shared__ float LM[256], LS[256];
    int m = blockIdx.x, tid = threadIdx.x;
    const float2* p = (const float2*)(ws + OFF_PART);
    float M = -3.4e38f, Ssum = 0.f;
    for (int nt = tid; nt < NTILES; nt += 256){
        float2 q = p[(long)m*NTILES + nt];
        if (q.x > M){ Ssum = Ssum*expf(M - q.x) + q.y; M = q.x; }
        else        { Ssum += q.y * expf(q.x - M); }
    }
    LM[tid] = M; LS[tid] = Ssum;
    __syncthreads();
    for (int off = 128; off >= 1; off >>= 1){
        if (tid < off){
            float m1 = LM[tid], s1 = LS[tid];
            float m2 = LM[tid+off], s2 = LS[tid+off];
            float mm = fmaxf(m1, m2);
            LM[tid] = mm;
            LS[tid] = s1*expf(m1-mm) + s2*expf(m2-mm);
        }
        __syncthreads();
    }
    float lse = LM[0] + logf(LS[0]);
    __syncthreads();
    int t = m >> 5, b = m & 31;
    int y = X[b*TT + t + 1];
    const float* cr = ws + OFF_CAT + m*1024;
    const float* wr = fcW + (long)y*1024;
    float a = 0.f;
    #pragma unroll
    for (int k = 0; k < 4; ++k) a += cr[tid*4+k]*wr[tid*4+k];
    LM[tid] = a;
    __syncthreads();
    for (int off = 128; off >= 1; off >>= 1){
        if (tid < off) LM[tid] += LM[tid+off];
        __syncthreads();
    }
    if (tid == 0){
        float tl = LM[0] + fcb[y];
        float nll = lse - tl;
        int valid = (y != 0);
        ws[OFF_NLL + m] = valid ? nll : 0.f;
        ws[OFF_CNT + m] = valid ? 1.f : 0.f;
    }
}

// ------------------------------------------------------------------ finalize
__global__ void k_fin(const float* __restrict__ ws, float* __restrict__ out){
    __shared__ float red[256];
    int tid = threadIdx.x;
    float lt = 0.f;
    if (tid < TM1){
        float s = 0.f, c = 0.f;
        for (int b=0;b<NB;b++){
            s += ws[OFF_NLL + tid*NB + b];
            c += ws[OFF_CNT + tid*NB + b];
        }
        lt = s / fmaxf(c, 1.f);
    }
    red[tid] = lt;
    __syncthreads();
    for (int off=128; off>=1; off>>=1){
        if (tid < off) red[tid] += red[tid+off];
        __syncthreads();
    }
    if (tid == 0) out[0] = red[0] / (float)TM1;
}

// -------------------------------------------------------------------- launch
extern "C" void kernel_launch(void* const* d_in, const int* in_sizes, int n_in,
                              void* d_out, int out_size, void* d_ws, size_t ws_size,
                              hipStream_t stream) {
    const int*   X     = (const int*)  d_in[0];
    const float* enc   = (const float*)d_in[1];
    const float* hid   = (const float*)d_in[2];
    const float* cel   = (const float*)d_in[3];
    const float* emb   = (const float*)d_in[4];
    const float* Wih0  = (const float*)d_in[5];
    const float* Whh0  = (const float*)d_in[6];
    const float* bih0  = (const float*)d_in[7];
    const float* bhh0  = (const float*)d_in[8];
    const float* Wih1  = (const float*)d_in[9];
    const float* Whh1  = (const float*)d_in[10];
    const float* bih1  = (const float*)d_in[11];
    const float* bhh1  = (const float*)d_in[12];
    const float* attnW = (const float*)d_in[13];
    const float* attnb = (const float*)d_in[14];
    const float* v     = (const float*)d_in[15];
    const float* fcW   = (const float*)d_in[16];
    const float* fcb   = (const float*)d_in[17];
    float* ws  = (float*)d_ws;
    float* out = (float*)d_out;

    k_init<<<128,256,0,stream>>>(hid, cel, ws);
    k_encw<<<dim3(8,64),256,0,stream>>>(enc, attnW, attnb, ws);
    for (int t = 0; t < TM1; ++t){
        int rb = t & 1, wb = (t+1) & 1;
        k_lstm0<<<64,256,0,stream>>>(X, emb, Wih0, Whh0, bih0, bhh0, ws, t, rb, wb);
        k_lstm1<<<64,256,0,stream>>>(Wih1, Whh1, bih1, bhh1, ws, t, rb, wb);
        k_attn<<<32,256,0,stream>>>(enc, attnW, v, ws, t, wb);
    }
    k_fc<<<dim3(NTILES,64),256,0,stream>>>(fcW, fcb, ws);
    k_row<<<NROWS,256,0,stream>>>(X, fcW, fcb, ws);
    k_fin<<<1,256,0,stream>>>(ws, out);
}

// Round 2
// 13443.188 us; speedup vs baseline: 2.2928x; 2.2928x over previous
//
#include <hip/hip_runtime.h>
#include <hip/hip_cooperative_groups.h>
#include <math.h>

namespace cg = cooperative_groups;

#define VOCAB 32000
#define EMB   256
#define HID   512
#define NB    32
#define TT    128
#define TM1   127
#define SS    128
#define NROWS (TM1*NB)     // 4064
#define NT128 250          // 32000/128

// ---- workspace layout (float32 offsets) ----
#define OFF_ENCW 0          // bf16 [32][128][512] (+attnb)
#define OFF_AWQT 1048576    // f32  [512][512]  attnW[:, :512] transposed
#define OFF_H0   1310720    // f32  [2][512][32] ping-pong, transposed
#define OFF_H1   1343488
#define OFF_C0   1376256    // f32  [512][32]
#define OFF_C1   1392640
#define OFF_G0X  1409024    // bf16 [127][2048][32]  emb@Wih0^T + biases, transposed
#define OFF_CATB 5570560    // bf16 [4096][1024]
#define OFF_PART 7667712    // float2 [4096][250]
#define OFF_NLL  9715712
#define OFF_CNT  9719776
// total 9,723,840 f32 = 38.9 MB

typedef __attribute__((ext_vector_type(8))) short short8;
typedef __attribute__((ext_vector_type(4))) float f32x4;

__device__ __forceinline__ float sigm(float x){ return 1.f/(1.f + __expf(-x)); }
__device__ __forceinline__ float tanh_f(float x){
    x = fminf(fmaxf(x, -15.f), 15.f);
    float e = __expf(2.f*x);
    return (e-1.f)/(e+1.f);
}
__device__ __forceinline__ unsigned short f2b(float f){
    union{float f; unsigned u;} x{f};
    unsigned r = (x.u + 0x7fff + ((x.u>>16)&1)) >> 16;
    return (unsigned short)r;
}
__device__ __forceinline__ float b2f(unsigned short b){
    union{unsigned u; float f;} x{(unsigned)b<<16};
    return x.f;
}

// ------------------------------------------------------------------ init
// states (transposed) + zero catb pad rows
__global__ void k_init(const float* __restrict__ hid, const float* __restrict__ cel,
                       float* __restrict__ ws){
    int idx = blockIdx.x*256 + threadIdx.x;
    if (idx < 2*HID*NB){
        int l = idx >> 14, r = idx & 16383;      // r = k*32+b
        int k = r >> 5, b = r & 31;
        float hv = 0.5f*(hid[(2*l)*(NB*HID) + b*HID + k] + hid[(2*l+1)*(NB*HID) + b*HID + k]);
        float cv = 0.5f*(cel[(2*l)*(NB*HID) + b*HID + k] + cel[(2*l+1)*(NB*HID) + b*HID + k]);
        if (l == 0){ ws[OFF_H0 + r] = hv; ws[OFF_C0 + r] = cv; }
        else       { ws[OFF_H1 + r] = hv; ws[OFF_C1 + r] = cv; }
    } else {
        int j = idx - 2*HID*NB;                   // 0..32767: pad rows 4064..4095
        if (j < 32*1024){
            unsigned short* catb = (unsigned short*)(ws + OFF_CATB);
            catb[(size_t)4064*1024 + j] = 0;
        }
    }
}

// ------------------------------------------------------------------ prep
// aWqT[k][h] = attnW[h][k]  (query half transpose)
__global__ void k_prep(const float* __restrict__ attnW, float* __restrict__ ws){
    int idx = blockIdx.x*256 + threadIdx.x;      // 262144
    int k = idx >> 9, h = idx & 511;
    ws[OFF_AWQT + k*512 + h] = attnW[h*1024 + k];
}

// ---------------------------------------------- encW = enc @ attnW[:,512:]^T + attnb  (bf16)
__global__ void k_encw(const float* __restrict__ enc, const float* __restrict__ attnW,
                       const float* __restrict__ attnb, float* __restrict__ ws){
    __shared__ float As[64][33];
    __shared__ float Bs[64][33];
    int tid = threadIdx.x;
    int nt = blockIdx.x, mt = blockIdx.y;
    int m0 = mt*64, n0 = nt*64;
    int ty = tid >> 4, tx = tid & 15;
    float acc[4][4] = {};
    for (int kk = 0; kk < 16; ++kk){
        int k0 = kk*32;
        #pragma unroll
        for (int i = 0; i < 8; ++i){
            int idx = tid + i*256;
            int r = idx >> 5, k = idx & 31;
            As[r][k] = enc[(m0+r)*HID + k0 + k];
            Bs[r][k] = attnW[(n0+r)*1024 + 512 + k0 + k];
        }
        __syncthreads();
        #pragma unroll
        for (int k = 0; k < 32; ++k){
            float av[4], bv[4];
            #pragma unroll
            for (int i=0;i<4;i++) av[i] = As[ty*4+i][k];
            #pragma unroll
            for (int j=0;j<4;j++) bv[j] = Bs[tx*4+j][k];
            #pragma unroll
            for (int i=0;i<4;i++)
                #pragma unroll
                for (int j=0;j<4;j++) acc[i][j] += av[i]*bv[j];
        }
        __syncthreads();
    }
    unsigned short* encwb = (unsigned short*)(ws + OFF_ENCW);
    #pragma unroll
    for (int i=0;i<4;i++)
      #pragma unroll
      for (int j=0;j<4;j++){
        int m = m0 + ty*4+i, n = n0 + tx*4+j;
        encwb[(size_t)m*512 + n] = f2b(acc[i][j] + attnb[n]);
      }
}

// ------------------------- g0x[t][row][b] = emb[X[b,t]] @ Wih0^T + bih0 + bhh0  (bf16, transposed)
__global__ void k_g0x(const int* __restrict__ X, const float* __restrict__ emb,
                      const float* __restrict__ Wih0, const float* __restrict__ bih0,
                      const float* __restrict__ bhh0, float* __restrict__ ws){
    __shared__ float As[64][33];
    __shared__ float Bs[64][33];
    int tid = threadIdx.x;
    int nt = blockIdx.x, mt = blockIdx.y;   // n: 32 tiles (2048), m: 64 tiles (4096)
    int m0 = mt*64, n0 = nt*64;
    int ty = tid >> 4, tx = tid & 15;
    float acc[4][4] = {};
    for (int kk = 0; kk < 8; ++kk){
        int k0 = kk*32;
        #pragma unroll
        for (int i = 0; i < 8; ++i){
            int idx = tid + i*256;
            int r = idx >> 5, k = idx & 31;
            int m = m0 + r;
            int tok = (m < NROWS) ? X[(m&31)*TT + (m>>5)] : 0;
            As[r][k] = emb[(size_t)tok*EMB + k0 + k];
            Bs[r][k] = Wih0[(n0+r)*EMB + k0 + k];
        }
        __syncthreads();
        #pragma unroll
        for (int k = 0; k < 32; ++k){
            float av[4], bv[4];
            #pragma unroll
            for (int i=0;i<4;i++) av[i] = As[ty*4+i][k];
            #pragma unroll
            for (int j=0;j<4;j++) bv[j] = Bs[tx*4+j][k];
            #pragma unroll
            for (int i=0;i<4;i++)
                #pragma unroll
                for (int j=0;j<4;j++) acc[i][j] += av[i]*bv[j];
        }
        __syncthreads();
    }
    unsigned short* g0xb = (unsigned short*)(ws + OFF_G0X);
    #pragma unroll
    for (int i=0;i<4;i++){
        int m = m0 + ty*4+i;
        if (m >= NROWS) continue;
        int t = m >> 5, b = m & 31;
        #pragma unroll
        for (int j=0;j<4;j++){
            int n = n0 + tx*4+j;
            g0xb[((size_t)t*2048 + n)*32 + b] = f2b(acc[i][j] + bih0[n] + bhh0[n]);
        }
    }
}

// ------------------------------------------------------------------ persistent scan
__global__ void __launch_bounds__(512)
k_scan(const float* __restrict__ enc, const float* __restrict__ Whh0,
       const float* __restrict__ Wih1, const float* __restrict__ Whh1,
       const float* __restrict__ bih1, const float* __restrict__ bhh1,
       const float* __restrict__ v, float* ws)
{
    cg::grid_group grid = cg::this_grid();
    const int blk = blockIdx.x, tid = threadIdx.x;
    __shared__ float red[512];
    __shared__ float h1s[512], hqv[512], attv[128];
    __shared__ float rbuf[2];
    unsigned short* catb = (unsigned short*)(ws + OFF_CATB);
    const unsigned short* g0xb = (const unsigned short*)(ws + OFF_G0X);
    const unsigned short* encwb = (const unsigned short*)(ws + OFF_ENCW);
    const float* aWqT = ws + OFF_AWQT;

    if (blk < 128){
        // ---------------- LSTM blocks: block owns 4 hidden units (all batches)
        const int b = tid & 31, jl = (tid>>5)&3, g = tid>>7;
        const int jglob = blk*4 + jl;
        const int grow = g*512 + jglob;
        const float4* w0  = (const float4*)(Whh0 + (size_t)grow*512);
        const float4* wa1 = (const float4*)(Wih1 + (size_t)grow*512);
        const float4* wb1 = (const float4*)(Whh1 + (size_t)grow*512);
        const float bsum1 = bih1[grow] + bhh1[grow];
        for (int t = 0; t < TM1; ++t){
            const int rb = t & 1, wb = rb ^ 1;
            // phase A: lstm0 gates (h-part) + cell
            {
                const float* h = ws + OFF_H0 + rb*16384;
                float acc = 0.f;
                #pragma unroll 4
                for (int k = 0; k < 512; k += 4){
                    float4 wv = w0[k>>2];
                    acc += h[(k+0)*32+b]*wv.x + h[(k+1)*32+b]*wv.y
                         + h[(k+2)*32+b]*wv.z + h[(k+3)*32+b]*wv.w;
                }
                red[g*128 + jl*32 + b] = acc;
            }
            __syncthreads();
            if (g == 0){
                const int off = jl*32 + b;
                const unsigned short* gx = g0xb + (size_t)t*65536;
                float gi = red[off]     + b2f(gx[(0*512+jglob)*32+b]);
                float gf = red[128+off] + b2f(gx[(1*512+jglob)*32+b]);
                float gg = red[256+off] + b2f(gx[(2*512+jglob)*32+b]);
                float go = red[384+off] + b2f(gx[(3*512+jglob)*32+b]);
                float c  = ws[OFF_C0 + jglob*32 + b];
                float cn = sigm(gf)*c + sigm(gi)*tanh_f(gg);
                float hn = sigm(go)*tanh_f(cn);
                ws[OFF_C0 + jglob*32 + b] = cn;
                ws[OFF_H0 + wb*16384 + jglob*32 + b] = hn;
            }
            grid.sync();
            // phase B: lstm1 gates + cell
            {
                const float* hA = ws + OFF_H0 + wb*16384;
                const float* hB = ws + OFF_H1 + rb*16384;
                float acc = bsum1;
                #pragma unroll 4
                for (int k = 0; k < 512; k += 4){
                    float4 wv = wa1[k>>2];
                    acc += hA[(k+0)*32+b]*wv.x + hA[(k+1)*32+b]*wv.y
                         + hA[(k+2)*32+b]*wv.z + hA[(k+3)*32+b]*wv.w;
                }
                #pragma unroll 4
                for (int k = 0; k < 512; k += 4){
                    float4 wv = wb1[k>>2];
                    acc += hB[(k+0)*32+b]*wv.x + hB[(k+1)*32+b]*wv.y
                         + hB[(k+2)*32+b]*wv.z + hB[(k+3)*32+b]*wv.w;
                }
                red[g*128 + jl*32 + b] = acc;
            }
            __syncthreads();
            if (g == 0){
                const int off = jl*32 + b;
                float gi = red[off], gf = red[128+off], gg = red[256+off], go = red[384+off];
                float c  = ws[OFF_C1 + jglob*32 + b];
                float cn = sigm(gf)*c + sigm(gi)*tanh_f(gg);
                float hn = sigm(go)*tanh_f(cn);
                ws[OFF_C1 + jglob*32 + b] = cn;
                ws[OFF_H1 + wb*16384 + jglob*32 + b] = hn;
                catb[((size_t)(t*32+b) << 10) + jglob] = f2b(hn);
            }
            grid.sync();
        }
    } else {
        // ---------------- attention blocks: one per batch element
        const int b = blk - 128;
        for (int t = 0; t < TM1; ++t){
            const int rb = t & 1;
            const int tm1 = t - 1;
            // phase A: scores for step t-1 (h1(t-1) lives in buffer rb)
            if (tm1 >= 0){
                h1s[tid] = ws[OFF_H1 + rb*16384 + tid*32 + b];
                __syncthreads();
                {
                    float a = 0.f;
                    #pragma unroll 8
                    for (int k = 0; k < 512; ++k) a += aWqT[k*512 + tid] * h1s[k];
                    hqv[tid] = a;
                }
                __syncthreads();
                {
                    const int s = tid >> 2, q = tid & 3;
                    const unsigned short* eb = encwb + ((size_t)(b*SS+s))*512 + q*128;
                    const float* hq = hqv + q*128;
                    const float* vp = v + q*128;
                    float p = 0.f;
                    #pragma unroll 4
                    for (int k = 0; k < 128; ++k) p += tanh_f(hq[k] + b2f(eb[k])) * vp[k];
                    p += __shfl_xor(p, 1);
                    p += __shfl_xor(p, 2);
                    if (q == 0) attv[s] = p;
                }
                __syncthreads();
            }
            grid.sync();
            // phase B: softmax + weighted sum for step t-1
            if (tm1 >= 0){
                float e0 = 0.f, e1 = 0.f;
                if (tid < 64){
                    float m2 = fmaxf(attv[tid], attv[tid+64]);
                    #pragma unroll
                    for (int msk = 32; msk >= 1; msk >>= 1) m2 = fmaxf(m2, __shfl_xor(m2, msk));
                    if (tid == 0) rbuf[0] = m2;
                }
                __syncthreads();
                float M = rbuf[0];
                if (tid < 64){
                    e0 = __expf(attv[tid] - M);
                    e1 = __expf(attv[tid+64] - M);
                    float sum = e0 + e1;
                    #pragma unroll
                    for (int msk = 32; msk >= 1; msk >>= 1) sum += __shfl_xor(sum, msk);
                    if (tid == 0) rbuf[1] = sum;
                }
                __syncthreads();
                float inv = 1.f / rbuf[1];
                if (tid < 64){ attv[tid] = e0*inv; attv[tid+64] = e1*inv; }
                __syncthreads();
                float wsum = 0.f;
                const float* ebase = enc + ((size_t)b*SS)*512 + tid;
                #pragma unroll 8
                for (int s = 0; s < 128; ++s) wsum += attv[s] * ebase[s*512];
                catb[((size_t)(tm1*32+b) << 10) + 512 + tid] = f2b(wsum);
            }
            grid.sync();
        }
        // final attention for t = 126 (h1 in buffer (126+1)&1 = 1)
        {
            const int tm1 = 126, hb = 1;
            h1s[tid] = ws[OFF_H1 + hb*16384 + tid*32 + b];
            __syncthreads();
            {
                float a = 0.f;
                #pragma unroll 8
                for (int k = 0; k < 512; ++k) a += aWqT[k*512 + tid] * h1s[k];
                hqv[tid] = a;
            }
            __syncthreads();
            {
                const int s = tid >> 2, q = tid & 3;
                const unsigned short* eb = encwb + ((size_t)(b*SS+s))*512 + q*128;
                const float* hq = hqv + q*128;
                const float* vp = v + q*128;
                float p = 0.f;
                #pragma unroll 4
                for (int k = 0; k < 128; ++k) p += tanh_f(hq[k] + b2f(eb[k])) * vp[k];
                p += __shfl_xor(p, 1);
                p += __shfl_xor(p, 2);
                if (q == 0) attv[s] = p;
            }
            __syncthreads();
            float e0 = 0.f, e1 = 0.f;
            if (tid < 64){
                float m2 = fmaxf(attv[tid], attv[tid+64]);
                #pragma unroll
                for (int msk = 32; msk >= 1; msk >>= 1) m2 = fmaxf(m2, __shfl_xor(m2, msk));
                if (tid == 0) rbuf[0] = m2;
            }
            __syncthreads();
            float M = rbuf[0];
            if (tid < 64){
                e0 = __expf(attv[tid] - M);
                e1 = __expf(attv[tid+64] - M);
                float sum = e0 + e1;
                #pragma unroll
                for (int msk = 32; msk >= 1; msk >>= 1) sum += __shfl_xor(sum, msk);
                if (tid == 0) rbuf[1] = sum;
            }
            __syncthreads();
            float inv = 1.f / rbuf[1];
            if (tid < 64){ attv[tid] = e0*inv; attv[tid+64] = e1*inv; }
            __syncthreads();
            float wsum = 0.f;
            const float* ebase = enc + ((size_t)b*SS)*512 + tid;
            #pragma unroll 8
            for (int s = 0; s < 128; ++s) wsum += attv[s] * ebase[s*512];
            catb[((size_t)(tm1*32+b) << 10) + 512 + tid] = f2b(wsum);
        }
    }
}

// ------------------------------------------------------------------ fc MFMA GEMM + LSE partials
// C[4096][32000] = catb @ fcW^T + fcb ; per (row, 128-tile): (max, sumexp)
__global__ void __launch_bounds__(256)
k_fc(const float* __restrict__ fcW, const float* __restrict__ fcb, float* __restrict__ ws){
    __shared__ unsigned short As[128*32];   // [r][32k] swizzled 16B slots
    __shared__ unsigned short Bs[128*32];
    __shared__ float eM[128], eS[128];
    const int tid = threadIdx.x;
    const int mt = blockIdx.x, nt = blockIdx.y;   // m fastest: B-panel L2 reuse
    const int m0 = mt*128, n0 = nt*128;
    const unsigned short* catb = (const unsigned short*)(ws + OFF_CATB);
    const int lane = tid & 63, wid = tid >> 6;
    const int wr = wid >> 1, wc = wid & 1;
    const int lr = lane & 15, lg = lane >> 4;
    // staging maps
    const int ar = tid & 127, ah = tid >> 7;   // A: row, 16-elem half
    const int br = tid >> 1,  bh = tid & 1;    // B: row, 16-elem half
    f32x4 acc[4][4];
    #pragma unroll
    for (int i=0;i<4;i++)
        #pragma unroll
        for (int j=0;j<4;j++) acc[i][j] = (f32x4){0.f,0.f,0.f,0.f};

    for (int kk = 0; kk < 32; ++kk){
        const int k0 = kk*32;
        // global loads (before barrier: overlap)
        uint4 a0 = *(const uint4*)(catb + (size_t)(m0+ar)*1024 + k0 + ah*16);
        uint4 a1 = *(const uint4*)(catb + (size_t)(m0+ar)*1024 + k0 + ah*16 + 8);
        const float* bsrc = fcW + (size_t)(n0+br)*1024 + k0 + bh*16;
        float4 f0 = *(const float4*)(bsrc);
        float4 f1 = *(const float4*)(bsrc+4);
        float4 f2 = *(const float4*)(bsrc+8);
        float4 f3 = *(const float4*)(bsrc+12);
        __syncthreads();   // prev iter frag reads done
        // A: slots 2ah, 2ah+1, swizzled
        {
            int swz = (ar>>1)&3;
            *(uint4*)&As[ar*32 + ((2*ah  )^swz)*8] = a0;
            *(uint4*)&As[ar*32 + ((2*ah+1)^swz)*8] = a1;
        }
        // B: f32->bf16 (truncate via v_perm), slots 2bh, 2bh+1, swizzled
        {
            uint4 p0, p1;
            p0.x = __builtin_amdgcn_perm(__float_as_uint(f0.y), __float_as_uint(f0.x), 0x07060302u);
            p0.y = __builtin_amdgcn_perm(__float_as_uint(f0.w), __float_as_uint(f0.z), 0x07060302u);
            p0.z = __builtin_amdgcn_perm(__float_as_uint(f1.y), __float_as_uint(f1.x), 0x07060302u);
            p0.w = __builtin_amdgcn_perm(__float_as_uint(f1.w), __float_as_uint(f1.z), 0x07060302u);
            p1.x = __builtin_amdgcn_perm(__float_as_uint(f2.y), __float_as_uint(f2.x), 0x07060302u);
            p1.y = __builtin_amdgcn_perm(__float_as_uint(f2.w), __float_as_uint(f2.z), 0x07060302u);
            p1.z = __builtin_amdgcn_perm(__float_as_uint(f3.y), __float_as_uint(f3.x), 0x07060302u);
            p1.w = __builtin_amdgcn_perm(__float_as_uint(f3.w), __float_as_uint(f3.z), 0x07060302u);
            int swz = (br>>1)&3;
            *(uint4*)&Bs[br*32 + ((2*bh  )^swz)*8] = p0;
            *(uint4*)&Bs[br*32 + ((2*bh+1)^swz)*8] = p1;
        }
        __syncthreads();
        short8 av[4], bv[4];
        #pragma unroll
        for (int mi=0; mi<4; ++mi){
            int r = wr*64 + mi*16 + lr;
            av[mi] = *(const short8*)&As[r*32 + ((lg ^ ((r>>1)&3))*8)];
        }
        #pragma unroll
        for (int ni=0; ni<4; ++ni){
            int r = wc*64 + ni*16 + lr;
            bv[ni] = *(const short8*)&Bs[r*32 + ((lg ^ ((r>>1)&3))*8)];
        }
        #pragma unroll
        for (int mi=0; mi<4; ++mi)
            #pragma unroll
            for (int ni=0; ni<4; ++ni)
                acc[mi][ni] = __builtin_amdgcn_mfma_f32_16x16x32_bf16(av[mi], bv[ni], acc[mi][ni], 0, 0, 0);
    }
    // epilogue: per-row (max, sumexp) over this 128-col tile
    float bias[4];
    #pragma unroll
    for (int ni=0; ni<4; ++ni) bias[ni] = fcb[n0 + wc*64 + ni*16 + lr];
    float mxA[4][4], smA[4][4];
    #pragma unroll
    for (int mi=0; mi<4; ++mi){
        #pragma unroll
        for (int reg=0; reg<4; ++reg){
            float mx = -3.4e38f;
            #pragma unroll
            for (int ni=0; ni<4; ++ni) mx = fmaxf(mx, acc[mi][ni][reg] + bias[ni]);
            #pragma unroll
            for (int msk=8; msk>=1; msk>>=1) mx = fmaxf(mx, __shfl_xor(mx, msk));
            float sm = 0.f;
            #pragma unroll
            for (int ni=0; ni<4; ++ni) sm += __expf(acc[mi][ni][reg] + bias[ni] - mx);
            #pragma unroll
            for (int msk=8; msk>=1; msk>>=1) sm += __shfl_xor(sm, msk);
            mxA[mi][reg] = mx; smA[mi][reg] = sm;
            if (wc == 0 && lr == 0){
                int rl = wr*64 + mi*16 + lg*4 + reg;
                eM[rl] = mx; eS[rl] = sm;
            }
        }
    }
    __syncthreads();
    if (wc == 1 && lr == 0){
        float2* part = (float2*)(ws + OFF_PART);
        #pragma unroll
        for (int mi=0; mi<4; ++mi){
            #pragma unroll
            for (int reg=0; reg<4; ++reg){
                int rl = wr*64 + mi*16 + lg*4 + reg;
                float m0v = eM[rl], s0 = eS[rl];
                float m1v = mxA[mi][reg], s1 = smA[mi][reg];
                float M = fmaxf(m0v, m1v);
                float S = s0*__expf(m0v - M) + s1*__expf(m1v - M);
                part[(size_t)(m0 + rl)*NT128 + nt] = make_float2(M, S);
            }
        }
    }
}

// ------------------------------------------- per-row LSE combine + target logit
__global__ void k_row(const int* __restrict__ X, const float* __restrict__ fcW,
                      const float* __restrict__ fcb, float* __restrict__ ws){
    __shared__ float LM[256], LS[256];
    int m = blockIdx.x, tid = threadIdx.x;
    const float2* p = (const float2*)(ws + OFF_PART);
    float M = -3.4e38f, Ssum = 0.f;
    if (tid < NT128){
        float2 q = p[(size_t)m*NT128 + tid];
        M = q.x; Ssum = q.y;
    }
    LM[tid] = M; LS[tid] = Ssum;
    __syncthreads();
    for (int off = 128; off >= 1; off >>= 1){
        if (tid < off){
            float m1 = LM[tid], s1 = LS[tid];
            float m2 = LM[tid+off], s2 = LS[tid+off];
            float mm = fmaxf(m1, m2);
            LM[tid] = mm;
            LS[tid] = s1*__expf(m1-mm) + s2*__expf(m2-mm);
        }
        __syncthreads();
    }
    float lse = LM[0] + __logf(LS[0]);
    __syncthreads();
    int t = m >> 5, b = m & 31;
    int y = X[b*TT + t + 1];
    const unsigned short* cr = (const unsigned short*)(ws + OFF_CATB) + (size_t)m*1024;
    const float* wr = fcW + (size_t)y*1024;
    float a = 0.f;
    #pragma unroll
    for (int k = 0; k < 4; ++k) a += b2f(cr[tid*4+k]) * wr[tid*4+k];
    LM[tid] = a;
    __syncthreads();
    for (int off = 128; off >= 1; off >>= 1){
        if (tid < off) LM[tid] += LM[tid+off];
        __syncthreads();
    }
    if (tid == 0){
        float tl = LM[0] + fcb[y];
        float nll = lse - tl;
        int valid = (y != 0);
        ws[OFF_NLL + m] = valid ? nll : 0.f;
        ws[OFF_CNT + m] = valid ? 1.f : 0.f;
    }
}

// ------------------------------------------------------------------ finalize
__global__ void k_fin(const float* __restrict__ ws, float* __restrict__ out){
    __shared__ float red[256];
    int tid = threadIdx.x;
    float lt = 0.f;
    if (tid < TM1){
        float s = 0.f, c = 0.f;
        for (int b=0;b<NB;b++){
            s += ws[OFF_NLL + tid*NB + b];
            c += ws[OFF_CNT + tid*NB + b];
        }
        lt = s / fmaxf(c, 1.f);
    }
    red[tid] = lt;
    __syncthreads();
    for (int off=128; off>=1; off>>=1){
        if (tid < off) red[tid] += red[tid+off];
        __syncthreads();
    }
    if (tid == 0) out[0] = red[0] / (float)TM1;
}

// -------------------------------------------------------------------- launch
extern "C" void kernel_launch(void* const* d_in, const int* in_sizes, int n_in,
                              void* d_out, int out_size, void* d_ws, size_t ws_size,
                              hipStream_t stream) {
    const int*   X     = (const int*)  d_in[0];
    const float* enc   = (const float*)d_in[1];
    const float* hid   = (const float*)d_in[2];
    const float* cel   = (const float*)d_in[3];
    const float* emb   = (const float*)d_in[4];
    const float* Wih0  = (const float*)d_in[5];
    const float* Whh0  = (const float*)d_in[6];
    const float* bih0  = (const float*)d_in[7];
    const float* bhh0  = (const float*)d_in[8];
    const float* Wih1  = (const float*)d_in[9];
    const float* Whh1  = (const float*)d_in[10];
    const float* bih1  = (const float*)d_in[11];
    const float* bhh1  = (const float*)d_in[12];
    const float* attnW = (const float*)d_in[13];
    const float* attnb = (const float*)d_in[14];
    const float* v     = (const float*)d_in[15];
    const float* fcW   = (const float*)d_in[16];
    const float* fcb   = (const float*)d_in[17];
    float* ws  = (float*)d_ws;
    float* out = (float*)d_out;

    k_init<<<256, 256, 0, stream>>>(hid, cel, ws);
    k_prep<<<1024, 256, 0, stream>>>(attnW, ws);
    k_encw<<<dim3(8,64), 256, 0, stream>>>(enc, attnW, attnb, ws);
    k_g0x<<<dim3(32,64), 256, 0, stream>>>(X, emb, Wih0, bih0, bhh0, ws);

    void* args[] = {(void*)&enc, (void*)&Whh0, (void*)&Wih1, (void*)&Whh1,
                    (void*)&bih1, (void*)&bhh1, (void*)&v, (void*)&ws};
    hipLaunchCooperativeKernel((const void*)k_scan, dim3(160), dim3(512), args, 0, stream);

    k_fc<<<dim3(32, NT128), 256, 0, stream>>>(fcW, fcb, ws);
    k_row<<<NROWS, 256, 0, stream>>>(X, fcW, fcb, ws);
    k_fin<<<1, 256, 0, stream>>>(ws, out);
}

// Round 3
// 7624.736 us; speedup vs baseline: 4.0424x; 1.7631x over previous
//
#include <hip/hip_runtime.h>
#include <hip/hip_cooperative_groups.h>
#include <math.h>

namespace cg = cooperative_groups;

#define VOCAB 32000
#define EMB   256
#define HID   512
#define NB    32
#define TT    128
#define TM1   127
#define SS    128
#define NROWS (TM1*NB)     // 4064
#define NT128 250          // 32000/128

// ---- workspace layout (float32 offsets) ----
#define OFF_ENCW 0          // bf16 [32][128][512] enc@attnW_enc^T + attnb
#define OFF_AWQT 1048576    // f32  [512][512]  attnW[:, :512] transposed
#define OFF_H0B  1310720    // bf16 [2][32][512] h0 ping-pong
#define OFF_H1B  1327104    // bf16 [2][32][512] h1 ping-pong
#define OFF_C0   1343488    // f32  [512][32]
#define OFF_C1   1359872    // f32  [512][32]
#define OFF_G0X  1376256    // bf16 [127][2048][32]  emb@Wih0^T + biases
#define OFF_CATB 5537792    // bf16 [4096][1024]
#define OFF_PART 7634944    // float2 [4096][250]
#define OFF_NLL  9682944
#define OFF_CNT  9687008
// end 9,691,072 f32 = 38.8 MB

typedef __attribute__((ext_vector_type(8))) short short8;
typedef __attribute__((ext_vector_type(4))) float f32x4;

__device__ __forceinline__ float sigm(float x){ return 1.f/(1.f + __expf(-x)); }
__device__ __forceinline__ float tanh_f(float x){
    x = fminf(fmaxf(x, -15.f), 15.f);
    float e = __expf(2.f*x);
    return (e-1.f)/(e+1.f);
}
__device__ __forceinline__ unsigned short f2b(float f){
    union{float f; unsigned u;} x{f};
    unsigned r = (x.u + 0x7fff + ((x.u>>16)&1)) >> 16;
    return (unsigned short)r;
}
__device__ __forceinline__ float b2f(unsigned short b){
    union{unsigned u; float f;} x{(unsigned)b<<16};
    return x.f;
}
__device__ __forceinline__ uint4 pack8(const float4 f0, const float4 f1){
    uint4 r;
    r.x = ((unsigned)f2b(f0.x)) | ((unsigned)f2b(f0.y)<<16);
    r.y = ((unsigned)f2b(f0.z)) | ((unsigned)f2b(f0.w)<<16);
    r.z = ((unsigned)f2b(f1.x)) | ((unsigned)f2b(f1.y)<<16);
    r.w = ((unsigned)f2b(f1.z)) | ((unsigned)f2b(f1.w)<<16);
    return r;
}

// ------------------------------------------------------------------ init
__global__ void k_init(const float* __restrict__ hid, const float* __restrict__ cel,
                       float* __restrict__ ws){
    int idx = blockIdx.x*256 + threadIdx.x;
    if (idx < 2*HID*NB){
        int l = idx >> 14, r = idx & 16383;      // r = k*32+b
        int k = r >> 5, b = r & 31;
        float hv = 0.5f*(hid[(2*l)*(NB*HID) + b*HID + k] + hid[(2*l+1)*(NB*HID) + b*HID + k]);
        float cv = 0.5f*(cel[(2*l)*(NB*HID) + b*HID + k] + cel[(2*l+1)*(NB*HID) + b*HID + k]);
        unsigned short* hb = (unsigned short*)(ws + (l==0 ? OFF_H0B : OFF_H1B));
        hb[b*512 + k] = f2b(hv);                 // buffer 0
        ws[(l==0 ? OFF_C0 : OFF_C1) + k*32 + b] = cv;
    } else {
        int j = idx - 2*HID*NB;                   // zero catb pad rows 4064..4095
        if (j < 32*1024){
            unsigned short* catb = (unsigned short*)(ws + OFF_CATB);
            catb[(size_t)4064*1024 + j] = 0;
        }
    }
}

// ------------------------------------------------------------------ prep
__global__ void k_prep(const float* __restrict__ attnW, float* __restrict__ ws){
    int idx = blockIdx.x*256 + threadIdx.x;      // 262144
    int k = idx >> 9, h = idx & 511;
    ws[OFF_AWQT + k*512 + h] = attnW[h*1024 + k];
}

// ---------------------------------------------- encW = enc @ attnW[:,512:]^T + attnb  (bf16)
__global__ void k_encw(const float* __restrict__ enc, const float* __restrict__ attnW,
                       const float* __restrict__ attnb, float* __restrict__ ws){
    __shared__ float As[64][33];
    __shared__ float Bs[64][33];
    int tid = threadIdx.x;
    int nt = blockIdx.x, mt = blockIdx.y;
    int m0 = mt*64, n0 = nt*64;
    int ty = tid >> 4, tx = tid & 15;
    float acc[4][4] = {};
    for (int kk = 0; kk < 16; ++kk){
        int k0 = kk*32;
        #pragma unroll
        for (int i = 0; i < 8; ++i){
            int idx = tid + i*256;
            int r = idx >> 5, k = idx & 31;
            As[r][k] = enc[(m0+r)*HID + k0 + k];
            Bs[r][k] = attnW[(n0+r)*1024 + 512 + k0 + k];
        }
        __syncthreads();
        #pragma unroll
        for (int k = 0; k < 32; ++k){
            float av[4], bv[4];
            #pragma unroll
            for (int i=0;i<4;i++) av[i] = As[ty*4+i][k];
            #pragma unroll
            for (int j=0;j<4;j++) bv[j] = Bs[tx*4+j][k];
            #pragma unroll
            for (int i=0;i<4;i++)
                #pragma unroll
                for (int j=0;j<4;j++) acc[i][j] += av[i]*bv[j];
        }
        __syncthreads();
    }
    unsigned short* encwb = (unsigned short*)(ws + OFF_ENCW);
    #pragma unroll
    for (int i=0;i<4;i++)
      #pragma unroll
      for (int j=0;j<4;j++){
        int m = m0 + ty*4+i, n = n0 + tx*4+j;
        encwb[(size_t)m*512 + n] = f2b(acc[i][j] + attnb[n]);
      }
}

// ------------------------- g0x[t][row][b] = emb[X[b,t]] @ Wih0^T + bih0 + bhh0  (bf16)
__global__ void k_g0x(const int* __restrict__ X, const float* __restrict__ emb,
                      const float* __restrict__ Wih0, const float* __restrict__ bih0,
                      const float* __restrict__ bhh0, float* __restrict__ ws){
    __shared__ float As[64][33];
    __shared__ float Bs[64][33];
    int tid = threadIdx.x;
    int nt = blockIdx.x, mt = blockIdx.y;   // n: 32 tiles (2048), m: 64 tiles (4096)
    int m0 = mt*64, n0 = nt*64;
    int ty = tid >> 4, tx = tid & 15;
    float acc[4][4] = {};
    for (int kk = 0; kk < 8; ++kk){
        int k0 = kk*32;
        #pragma unroll
        for (int i = 0; i < 8; ++i){
            int idx = tid + i*256;
            int r = idx >> 5, k = idx & 31;
            int m = m0 + r;
            int tok = (m < NROWS) ? X[(m&31)*TT + (m>>5)] : 0;
            As[r][k] = emb[(size_t)tok*EMB + k0 + k];
            Bs[r][k] = Wih0[(n0+r)*EMB + k0 + k];
        }
        __syncthreads();
        #pragma unroll
        for (int k = 0; k < 32; ++k){
            float av[4], bv[4];
            #pragma unroll
            for (int i=0;i<4;i++) av[i] = As[ty*4+i][k];
            #pragma unroll
            for (int j=0;j<4;j++) bv[j] = Bs[tx*4+j][k];
            #pragma unroll
            for (int i=0;i<4;i++)
                #pragma unroll
                for (int j=0;j<4;j++) acc[i][j] += av[i]*bv[j];
        }
        __syncthreads();
    }
    unsigned short* g0xb = (unsigned short*)(ws + OFF_G0X);
    #pragma unroll
    for (int i=0;i<4;i++){
        int m = m0 + ty*4+i;
        if (m >= NROWS) continue;
        int t = m >> 5, b = m & 31;
        #pragma unroll
        for (int j=0;j<4;j++){
            int n = n0 + tx*4+j;
            g0xb[((size_t)t*2048 + n)*32 + b] = f2b(acc[i][j] + bih0[n] + bhh0[n]);
        }
    }
}

// ------------------------------------------------------------------ persistent scan
// Pipeline per grid-sync interval i (0..128):
//   blocks   0..63  : lstm0 step t0=i      (i<=126)   64 blocks x 8 units, W0 in LDS
//   blocks  64..191 : lstm1 step t1=i-1    (1<=i<=127) 128 blocks x 4 units, W1 in LDS
//   blocks 192..223 : attn  step ta=i-2    (2<=i<=128) 32 blocks (1/batch)
__global__ void __launch_bounds__(512, 1)
k_scan(const float* __restrict__ enc, const float* __restrict__ Whh0,
       const float* __restrict__ Wih1, const float* __restrict__ Whh1,
       const float* __restrict__ bih1, const float* __restrict__ bhh1,
       const float* __restrict__ v, float* ws)
{
    cg::grid_group grid = cg::this_grid();
    const int blk = blockIdx.x, tid = threadIdx.x;
    __shared__ __align__(16) char smem[55296];
    unsigned short* catb  = (unsigned short*)(ws + OFF_CATB);
    const unsigned short* g0xb  = (const unsigned short*)(ws + OFF_G0X);
    const unsigned short* encwb = (const unsigned short*)(ws + OFF_ENCW);
    unsigned short* h0b = (unsigned short*)(ws + OFF_H0B);   // [2][32][512]
    unsigned short* h1b = (unsigned short*)(ws + OFF_H1B);

    if (blk < 64){
        // ================= lstm0: 8 units, 32 gate-rows, K=512 =================
        unsigned short* Ws = (unsigned short*)smem;            // [32][512] bf16 swizzled
        float* red  = (float*)(smem + 32768);                  // [8w][2nt][64][4] = 16KB
        float* gbuf = (float*)(smem + 49152);                  // [32][33]
        const int u0 = blk*8;
        {   // stage weights once: row n = g*8+j <-> Whh0 row g*512+u0+j
            int n = tid >> 4, q = tid & 15;
            int g = n >> 3, j = n & 7;
            const float* src = Whh0 + ((size_t)(g*512 + u0 + j))*512 + q*32;
            #pragma unroll
            for (int c = 0; c < 4; ++c){
                float4 f0 = *(const float4*)(src + c*8);
                float4 f1 = *(const float4*)(src + c*8 + 4);
                int s = q*4 + c;
                *(uint4*)&Ws[n*512 + ((s ^ (n&7))<<3)] = pack8(f0, f1);
            }
        }
        __syncthreads();
        const int w = tid >> 6, lane = tid & 63;
        const int mt = w & 1, kg = w >> 1;
        const int lr = lane & 15, lg = lane >> 4;
        for (int i = 0; i <= 128; ++i){
            if (i <= 126){
                const int t0 = i, p = i & 1;
                const unsigned short* hsrc = h0b + p*16384;
                f32x4 acc0 = {0.f,0.f,0.f,0.f}, acc1 = {0.f,0.f,0.f,0.f};
                #pragma unroll
                for (int ks = 0; ks < 4; ++ks){
                    int kk = kg*4 + ks;
                    short8 a = *(const short8*)(hsrc + (mt*16+lr)*512 + kk*32 + lg*8);
                    int sl = kk*4 + lg;
                    short8 b0 = *(const short8*)&Ws[lr*512      + ((sl ^ (lr&7))<<3)];
                    short8 b1 = *(const short8*)&Ws[(16+lr)*512 + ((sl ^ ((16+lr)&7))<<3)];
                    acc0 = __builtin_amdgcn_mfma_f32_16x16x32_bf16(a, b0, acc0, 0,0,0);
                    acc1 = __builtin_amdgcn_mfma_f32_16x16x32_bf16(a, b1, acc1, 0,0,0);
                }
                *(f32x4*)&red[((w*2+0)*64 + lane)*4] = acc0;
                *(f32x4*)&red[((w*2+1)*64 + lane)*4] = acc1;
                __syncthreads();
                #pragma unroll
                for (int o = tid; o < 1024; o += 512){
                    int reg = o & 3, ln = (o>>2) & 63, ntl = (o>>8)&1, mtl = o>>9;
                    float s = 0.f;
                    #pragma unroll
                    for (int kg2 = 0; kg2 < 4; ++kg2)
                        s += red[(((kg2*2+mtl)*2 + ntl)*64 + ln)*4 + reg];
                    int bb = mtl*16 + (ln>>4)*4 + reg;
                    int nn = ntl*16 + (ln & 15);
                    gbuf[bb*33 + nn] = s;
                }
                __syncthreads();
                if (tid < 256){
                    int j = tid >> 5, b = tid & 31;
                    int u = u0 + j;
                    const unsigned short* gx = g0xb + (size_t)t0*65536;
                    float gi = gbuf[b*33 + 0*8 + j] + b2f(gx[(0*512+u)*32 + b]);
                    float gf = gbuf[b*33 + 1*8 + j] + b2f(gx[(1*512+u)*32 + b]);
                    float gg = gbuf[b*33 + 2*8 + j] + b2f(gx[(2*512+u)*32 + b]);
                    float go = gbuf[b*33 + 3*8 + j] + b2f(gx[(3*512+u)*32 + b]);
                    float c  = ws[OFF_C0 + u*32 + b];
                    float cn = sigm(gf)*c + sigm(gi)*tanh_f(gg);
                    float hn = sigm(go)*tanh_f(cn);
                    ws[OFF_C0 + u*32 + b] = cn;
                    h0b[(p^1)*16384 + b*512 + u] = f2b(hn);
                }
            }
            if (i < 128) grid.sync();
        }
    } else if (blk < 192){
        // ================= lstm1: 4 units, 16 gate-rows, K=1024 =================
        unsigned short* Ws = (unsigned short*)smem;            // [16][1024] bf16 swizzled
        float* red  = (float*)(smem + 32768);                  // [8w][64][4] = 8KB
        float* gbuf = (float*)(smem + 40960);                  // [32][17]
        float* bs   = (float*)(smem + 43264);                  // [16]
        const int u0 = (blk - 64)*4;
        {   // stage weights: row n = g*4+j <-> [Wih1;Whh1] row g*512+u0+j
            int n = tid >> 5, q = tid & 31;
            int g = n >> 2, j = n & 3;
            int grow = g*512 + u0 + j;
            int k0 = q*32;
            const float* src = (k0 < 512) ? (Wih1 + (size_t)grow*512 + k0)
                                          : (Whh1 + (size_t)grow*512 + (k0-512));
            #pragma unroll
            for (int c = 0; c < 4; ++c){
                float4 f0 = *(const float4*)(src + c*8);
                float4 f1 = *(const float4*)(src + c*8 + 4);
                int s = q*4 + c;
                *(uint4*)&Ws[n*1024 + ((s ^ (n&7))<<3)] = pack8(f0, f1);
            }
            if (tid < 16){
                int gg = tid >> 2, jj = tid & 3;
                int gr = gg*512 + u0 + jj;
                bs[tid] = bih1[gr] + bhh1[gr];
            }
        }
        __syncthreads();
        const int w = tid >> 6, lane = tid & 63;
        const int mt = w & 1, kg = w >> 1;
        const int lr = lane & 15, lg = lane >> 4;
        for (int i = 0; i <= 128; ++i){
            if (i >= 1 && i <= 127){
                const int t1 = i - 1;
                const unsigned short* h0src = h0b + (i&1)*16384;
                const unsigned short* h1src = h1b + ((i-1)&1)*16384;
                f32x4 acc = {0.f,0.f,0.f,0.f};
                #pragma unroll
                for (int ks = 0; ks < 8; ++ks){
                    int kk = kg*8 + ks;
                    const unsigned short* hs = (kk < 16)
                        ? (h0src + (mt*16+lr)*512 + kk*32 + lg*8)
                        : (h1src + (mt*16+lr)*512 + (kk-16)*32 + lg*8);
                    short8 a = *(const short8*)hs;
                    int sl = kk*4 + lg;
                    short8 b0 = *(const short8*)&Ws[lr*1024 + ((sl ^ (lr&7))<<3)];
                    acc = __builtin_amdgcn_mfma_f32_16x16x32_bf16(a, b0, acc, 0,0,0);
                }
                *(f32x4*)&red[(w*64 + lane)*4] = acc;
                __syncthreads();
                {
                    int o = tid;
                    int reg = o & 3, ln = (o>>2) & 63, mtl = o>>8;
                    float s = 0.f;
                    #pragma unroll
                    for (int kg2 = 0; kg2 < 4; ++kg2)
                        s += red[((kg2*2+mtl)*64 + ln)*4 + reg];
                    int bb = mtl*16 + (ln>>4)*4 + reg;
                    int nn = ln & 15;
                    gbuf[bb*17 + nn] = s;
                }
                __syncthreads();
                if (tid < 128){
                    int j = tid >> 5, b = tid & 31;
                    int u = u0 + j;
                    float gi = gbuf[b*17 + 0*4 + j] + bs[0*4 + j];
                    float gf = gbuf[b*17 + 1*4 + j] + bs[1*4 + j];
                    float gg = gbuf[b*17 + 2*4 + j] + bs[2*4 + j];
                    float go = gbuf[b*17 + 3*4 + j] + bs[3*4 + j];
                    float c  = ws[OFF_C1 + u*32 + b];
                    float cn = sigm(gf)*c + sigm(gi)*tanh_f(gg);
                    float hn = sigm(go)*tanh_f(cn);
                    ws[OFF_C1 + u*32 + b] = cn;
                    h1b[(i&1)*16384 + b*512 + u] = f2b(hn);
                    catb[((size_t)(t1*32 + b) << 10) + u] = f2b(hn);
                }
            }
            if (i < 128) grid.sync();
        }
    } else {
        // ================= attention: one block per batch =================
        float* h1s  = (float*)smem;           // 512
        float* hqv  = (float*)(smem + 2048);  // 512
        float* attv = (float*)(smem + 4096);  // 128
        float* rbuf = (float*)(smem + 4608);  // 2
        const int b = blk - 192;
        const float* aWqT = ws + OFF_AWQT;
        for (int i = 0; i <= 128; ++i){
            if (i >= 2){
                const int ta = i - 2;
                h1s[tid] = b2f(h1b[((i+1)&1)*16384 + b*512 + tid]);
                __syncthreads();
                {
                    float a0=0.f,a1=0.f,a2=0.f,a3=0.f;
                    const float* ap = aWqT + tid;
                    #pragma unroll 4
                    for (int k = 0; k < 512; k += 4){
                        a0 += ap[(k+0)*512] * h1s[k+0];
                        a1 += ap[(k+1)*512] * h1s[k+1];
                        a2 += ap[(k+2)*512] * h1s[k+2];
                        a3 += ap[(k+3)*512] * h1s[k+3];
                    }
                    hqv[tid] = (a0+a1)+(a2+a3);
                }
                __syncthreads();
                {
                    const int s = tid >> 2, q = tid & 3;
                    const unsigned short* eb = encwb + ((size_t)(b*SS+s))*512 + q*128;
                    const float* hq = hqv + q*128;
                    const float* vp = v + q*128;
                    float p0 = 0.f, p1 = 0.f;
                    #pragma unroll 2
                    for (int k = 0; k < 128; k += 2){
                        p0 += tanh_f(hq[k]   + b2f(eb[k]))   * vp[k];
                        p1 += tanh_f(hq[k+1] + b2f(eb[k+1])) * vp[k+1];
                    }
                    float p = p0 + p1;
                    p += __shfl_xor(p, 1);
                    p += __shfl_xor(p, 2);
                    if (q == 0) attv[s] = p;
                }
                __syncthreads();
                float e0 = 0.f, e1 = 0.f;
                if (tid < 64){
                    float m2 = fmaxf(attv[tid], attv[tid+64]);
                    #pragma unroll
                    for (int msk = 32; msk >= 1; msk >>= 1) m2 = fmaxf(m2, __shfl_xor(m2, msk));
                    if (tid == 0) rbuf[0] = m2;
                }
                __syncthreads();
                float M = rbuf[0];
                if (tid < 64){
                    e0 = __expf(attv[tid] - M);
                    e1 = __expf(attv[tid+64] - M);
                    float sum = e0 + e1;
                    #pragma unroll
                    for (int msk = 32; msk >= 1; msk >>= 1) sum += __shfl_xor(sum, msk);
                    if (tid == 0) rbuf[1] = sum;
                }
                __syncthreads();
                if (tid < 64){
                    float inv = 1.f / rbuf[1];
                    attv[tid] = e0*inv; attv[tid+64] = e1*inv;
                }
                __syncthreads();
                {
                    float w0=0.f,w1=0.f,w2=0.f,w3=0.f;
                    const float* ebase = enc + ((size_t)b*SS)*512 + tid;
                    #pragma unroll 4
                    for (int s = 0; s < 128; s += 4){
                        w0 += attv[s]   * ebase[(s  )*512];
                        w1 += attv[s+1] * ebase[(s+1)*512];
                        w2 += attv[s+2] * ebase[(s+2)*512];
                        w3 += attv[s+3] * ebase[(s+3)*512];
                    }
                    catb[((size_t)(ta*32 + b) << 10) + 512 + tid] = f2b((w0+w1)+(w2+w3));
                }
                __syncthreads();
            }
            if (i < 128) grid.sync();
        }
    }
}

// ------------------------------------------------------------------ fc MFMA GEMM + LSE partials
__global__ void __launch_bounds__(256)
k_fc(const float* __restrict__ fcW, const float* __restrict__ fcb, float* __restrict__ ws){
    __shared__ unsigned short As[128*32];
    __shared__ unsigned short Bs[128*32];
    __shared__ float eM[128], eS[128];
    const int tid = threadIdx.x;
    const int mt = blockIdx.x, nt = blockIdx.y;
    const int m0 = mt*128, n0 = nt*128;
    const unsigned short* catb = (const unsigned short*)(ws + OFF_CATB);
    const int lane = tid & 63, wid = tid >> 6;
    const int wr = wid >> 1, wc = wid & 1;
    const int lr = lane & 15, lg = lane >> 4;
    const int ar = tid & 127, ah = tid >> 7;
    const int br = tid >> 1,  bh = tid & 1;
    f32x4 acc[4][4];
    #pragma unroll
    for (int i=0;i<4;i++)
        #pragma unroll
        for (int j=0;j<4;j++) acc[i][j] = (f32x4){0.f,0.f,0.f,0.f};

    for (int kk = 0; kk < 32; ++kk){
        const int k0 = kk*32;
        uint4 a0 = *(const uint4*)(catb + (size_t)(m0+ar)*1024 + k0 + ah*16);
        uint4 a1 = *(const uint4*)(catb + (size_t)(m0+ar)*1024 + k0 + ah*16 + 8);
        const float* bsrc = fcW + (size_t)(n0+br)*1024 + k0 + bh*16;
        float4 f0 = *(const float4*)(bsrc);
        float4 f1 = *(const float4*)(bsrc+4);
        float4 f2 = *(const float4*)(bsrc+8);
        float4 f3 = *(const float4*)(bsrc+12);
        __syncthreads();
        {
            int swz = (ar>>1)&3;
            *(uint4*)&As[ar*32 + ((2*ah  )^swz)*8] = a0;
            *(uint4*)&As[ar*32 + ((2*ah+1)^swz)*8] = a1;
        }
        {
            uint4 p0, p1;
            p0.x = __builtin_amdgcn_perm(__float_as_uint(f0.y), __float_as_uint(f0.x), 0x07060302u);
            p0.y = __builtin_amdgcn_perm(__float_as_uint(f0.w), __float_as_uint(f0.z), 0x07060302u);
            p0.z = __builtin_amdgcn_perm(__float_as_uint(f1.y), __float_as_uint(f1.x), 0x07060302u);
            p0.w = __builtin_amdgcn_perm(__float_as_uint(f1.w), __float_as_uint(f1.z), 0x07060302u);
            p1.x = __builtin_amdgcn_perm(__float_as_uint(f2.y), __float_as_uint(f2.x), 0x07060302u);
            p1.y = __builtin_amdgcn_perm(__float_as_uint(f2.w), __float_as_uint(f2.z), 0x07060302u);
            p1.z = __builtin_amdgcn_perm(__float_as_uint(f3.y), __float_as_uint(f3.x), 0x07060302u);
            p1.w = __builtin_amdgcn_perm(__float_as_uint(f3.w), __float_as_uint(f3.z), 0x07060302u);
            int swz = (br>>1)&3;
            *(uint4*)&Bs[br*32 + ((2*bh  )^swz)*8] = p0;
            *(uint4*)&Bs[br*32 + ((2*bh+1)^swz)*8] = p1;
        }
        __syncthreads();
        short8 av[4], bv[4];
        #pragma unroll
        for (int mi=0; mi<4; ++mi){
            int r = wr*64 + mi*16 + lr;
            av[mi] = *(const short8*)&As[r*32 + ((lg ^ ((r>>1)&3))*8)];
        }
        #pragma unroll
        for (int ni=0; ni<4; ++ni){
            int r = wc*64 + ni*16 + lr;
            bv[ni] = *(const short8*)&Bs[r*32 + ((lg ^ ((r>>1)&3))*8)];
        }
        #pragma unroll
        for (int mi=0; mi<4; ++mi)
            #pragma unroll
            for (int ni=0; ni<4; ++ni)
                acc[mi][ni] = __builtin_amdgcn_mfma_f32_16x16x32_bf16(av[mi], bv[ni], acc[mi][ni], 0, 0, 0);
    }
    float bias[4];
    #pragma unroll
    for (int ni=0; ni<4; ++ni) bias[ni] = fcb[n0 + wc*64 + ni*16 + lr];
    float mxA[4][4], smA[4][4];
    #pragma unroll
    for (int mi=0; mi<4; ++mi){
        #pragma unroll
        for (int reg=0; reg<4; ++reg){
            float mx = -3.4e38f;
            #pragma unroll
            for (int ni=0; ni<4; ++ni) mx = fmaxf(mx, acc[mi][ni][reg] + bias[ni]);
            #pragma unroll
            for (int msk=8; msk>=1; msk>>=1) mx = fmaxf(mx, __shfl_xor(mx, msk));
            float sm = 0.f;
            #pragma unroll
            for (int ni=0; ni<4; ++ni) sm += __expf(acc[mi][ni][reg] + bias[ni] - mx);
            #pragma unroll
            for (int msk=8; msk>=1; msk>>=1) sm += __shfl_xor(sm, msk);
            mxA[mi][reg] = mx; smA[mi][reg] = sm;
            if (wc == 0 && lr == 0){
                int rl = wr*64 + mi*16 + lg*4 + reg;
                eM[rl] = mx; eS[rl] = sm;
            }
        }
    }
    __syncthreads();
    if (wc == 1 && lr == 0){
        float2* part = (float2*)(ws + OFF_PART);
        #pragma unroll
        for (int mi=0; mi<4; ++mi){
            #pragma unroll
            for (int reg=0; reg<4; ++reg){
                int rl = wr*64 + mi*16 + lg*4 + reg;
                float m0v = eM[rl], s0 = eS[rl];
                float m1v = mxA[mi][reg], s1 = smA[mi][reg];
                float M = fmaxf(m0v, m1v);
                float S = s0*__expf(m0v - M) + s1*__expf(m1v - M);
                part[(size_t)(m0 + rl)*NT128 + nt] = make_float2(M, S);
            }
        }
    }
}

// ------------------------------------------- per-row LSE combine + target logit
__global__ void k_row(const int* __restrict__ X, const float* __restrict__ fcW,
                      const float* __restrict__ fcb, float* __restrict__ ws){
    __shared__ float LM[256], LS[256];
    int m = blockIdx.x, tid = threadIdx.x;
    const float2* p = (const float2*)(ws + OFF_PART);
    float M = -3.4e38f, Ssum = 0.f;
    if (tid < NT128){
        float2 q = p[(size_t)m*NT128 + tid];
        M = q.x; Ssum = q.y;
    }
    LM[tid] = M; LS[tid] = Ssum;
    __syncthreads();
    for (int off = 128; off >= 1; off >>= 1){
        if (tid < off){
            float m1 = LM[tid], s1 = LS[tid];
            float m2 = LM[tid+off], s2 = LS[tid+off];
            float mm = fmaxf(m1, m2);
            LM[tid] = mm;
            LS[tid] = s1*__expf(m1-mm) + s2*__expf(m2-mm);
        }
        __syncthreads();
    }
    float lse = LM[0] + __logf(LS[0]);
    __syncthreads();
    int t = m >> 5, b = m & 31;
    int y = X[b*TT + t + 1];
    const unsigned short* cr = (const unsigned short*)(ws + OFF_CATB) + (size_t)m*1024;
    const float* wr = fcW + (size_t)y*1024;
    float a = 0.f;
    #pragma unroll
    for (int k = 0; k < 4; ++k) a += b2f(cr[tid*4+k]) * wr[tid*4+k];
    LM[tid] = a;
    __syncthreads();
    for (int off = 128; off >= 1; off >>= 1){
        if (tid < off) LM[tid] += LM[tid+off];
        __syncthreads();
    }
    if (tid == 0){
        float tl = LM[0] + fcb[y];
        float nll = lse - tl;
        int valid = (y != 0);
        ws[OFF_NLL + m] = valid ? nll : 0.f;
        ws[OFF_CNT + m] = valid ? 1.f : 0.f;
    }
}

// ------------------------------------------------------------------ finalize
__global__ void k_fin(const float* __restrict__ ws, float* __restrict__ out){
    __shared__ float red[256];
    int tid = threadIdx.x;
    float lt = 0.f;
    if (tid < TM1){
        float s = 0.f, c = 0.f;
        for (int b=0;b<NB;b++){
            s += ws[OFF_NLL + tid*NB + b];
            c += ws[OFF_CNT + tid*NB + b];
        }
        lt = s / fmaxf(c, 1.f);
    }
    red[tid] = lt;
    __syncthreads();
    for (int off=128; off>=1; off>>=1){
        if (tid < off) red[tid] += red[tid+off];
        __syncthreads();
    }
    if (tid == 0) out[0] = red[0] / (float)TM1;
}

// -------------------------------------------------------------------- launch
extern "C" void kernel_launch(void* const* d_in, const int* in_sizes, int n_in,
                              void* d_out, int out_size, void* d_ws, size_t ws_size,
                              hipStream_t stream) {
    const int*   X     = (const int*)  d_in[0];
    const float* enc   = (const float*)d_in[1];
    const float* hid   = (const float*)d_in[2];
    const float* cel   = (const float*)d_in[3];
    const float* emb   = (const float*)d_in[4];
    const float* Wih0  = (const float*)d_in[5];
    const float* Whh0  = (const float*)d_in[6];
    const float* bih0  = (const float*)d_in[7];
    const float* bhh0  = (const float*)d_in[8];
    const float* Wih1  = (const float*)d_in[9];
    const float* Whh1  = (const float*)d_in[10];
    const float* bih1  = (const float*)d_in[11];
    const float* bhh1  = (const float*)d_in[12];
    const float* attnW = (const float*)d_in[13];
    const float* attnb = (const float*)d_in[14];
    const float* v     = (const float*)d_in[15];
    const float* fcW   = (const float*)d_in[16];
    const float* fcb   = (const float*)d_in[17];
    float* ws  = (float*)d_ws;
    float* out = (float*)d_out;

    k_init<<<256, 256, 0, stream>>>(hid, cel, ws);
    k_prep<<<1024, 256, 0, stream>>>(attnW, ws);
    k_encw<<<dim3(8,64), 256, 0, stream>>>(enc, attnW, attnb, ws);
    k_g0x<<<dim3(32,64), 256, 0, stream>>>(X, emb, Wih0, bih0, bhh0, ws);

    void* args[] = {(void*)&enc, (void*)&Whh0, (void*)&Wih1, (void*)&Whh1,
                    (void*)&bih1, (void*)&bhh1, (void*)&v, (void*)&ws};
    hipLaunchCooperativeKernel((const void*)k_scan, dim3(224), dim3(512), args, 0, stream);

    k_fc<<<dim3(32, NT128), 256, 0, stream>>>(fcW, fcb, ws);
    k_row<<<NROWS, 256, 0, stream>>>(X, fcW, fcb, ws);
    k_fin<<<1, 256, 0, stream>>>(ws, out);
}